// Round 13
// baseline (2245.860 us; speedup 1.0000x reference)
//
#include <hip/hip_runtime.h>
#include <hip/hip_bf16.h>

#define D_DIM 512
#define H_DIM 512
#define G_SEG 1024
#define BM    32

typedef __attribute__((ext_vector_type(8))) short bf16x8;
typedef __attribute__((ext_vector_type(4))) float f32x4;
typedef unsigned int u32;
typedef unsigned short u16;

// ---- workspace ----
#define WS_S   0         // G f32
#define WS_WB  8192      // 512 KB bf16 W in MFMA-fragment granule layout

// ---- LDS (static): bf16 A-copy + beta/ebs/sidx + per-wave flush scratch ----
#define AS_BYTES  (BM * 1024)                 // 32 rows x 64 granules x 16B
#define BETA_OFF  AS_BYTES                    // 4 col-groups x 32 f32
#define EBS_OFF   (BETA_OFF + 4 * BM * 4)
#define SIDX_OFF  (EBS_OFF + BM * 4)
#define SCR_OFF   (SIDX_OFF + BM * 4)         // 4 waves x 1KB
#define LDS_TOTAL (SCR_OFF + 4 * 1024)        // 37632 B -> 4 blocks/CU

static __device__ __forceinline__ u16 f2bf(float f) {
    __hip_bfloat16 h = __float2bfloat16(f);
    return *(u16*)&h;
}
static __device__ __forceinline__ float bf2f(u16 u) {
    return __uint_as_float(((u32)u) << 16);
}
static __device__ __forceinline__ float fast_tanh(float x) {
    float e = exp2f(x * 2.885390081777927f);   // e^(2x)
    return 1.0f - 2.0f * __builtin_amdgcn_rcpf(e + 1.0f);
}
static __device__ __forceinline__ bf16x8 cvt8(const float4& a, const float4& b) {
    union { u16 h[8]; bf16x8 v; } u;
    u.h[0]=f2bf(a.x); u.h[1]=f2bf(a.y); u.h[2]=f2bf(a.z); u.h[3]=f2bf(a.w);
    u.h[4]=f2bf(b.x); u.h[5]=f2bf(b.y); u.h[6]=f2bf(b.z); u.h[7]=f2bf(b.w);
    return u.v;
}

// ---- W fp32 -> bf16 granule layout: byte ((k32*512 + c)*4 + lhi)*16 = W[c][k32*32+lhi*8 ..+8]
__global__ __launch_bounds__(256)
void cvt_w(const float* __restrict__ W, u16* __restrict__ Wb) {
    int t   = blockIdx.x * 256 + threadIdx.x;
    int lhi = t & 3;
    int c   = (t >> 2) & 511;
    int k32 = t >> 11;
    const float* src = W + (size_t)c * 512 + k32 * 32 + lhi * 8;
    bf16x8 v = cvt8(*(const float4*)src, *(const float4*)(src + 4));
    *(bf16x8*)(Wb + (size_t)t * 8) = v;
}

// ---- fused: 32-row tile, barrier-free K-loop, A global->reg, 4 blocks/CU ----
__global__ __launch_bounds__(256, 4)
void fused(const float* __restrict__ E, const int* __restrict__ BI,
           const u16* __restrict__ Wb, const float* __restrict__ V,
           float* __restrict__ out, float* __restrict__ S)
{
    __shared__ char smem[LDS_TOTAL];
    const int tid = threadIdx.x;
    const int l   = tid & 63;
    const int w   = tid >> 6;     // col group: cols [w*128, +128)
    const int l15 = l & 15;
    const int lhi = l >> 4;
    const int nodeBase = blockIdx.x * BM;

    const float* Eb   = E + (size_t)nodeBase * 512;
    const float* aSrc = Eb + (size_t)l15 * 512 + lhi * 8;   // + m*16*512 + kk*32
    const int bOffBase = ((w * 128 + l15) * 4 + lhi) * 16;  // + n*1024
    const char* Wbb = (const char*)Wb;

    float Vv[8];
#pragma unroll
    for (int n = 0; n < 8; ++n)
        Vv[n] = V[w * 128 + n * 16 + l15];

    f32x4 acc[2][8];
#pragma unroll
    for (int m = 0; m < 2; ++m)
#pragma unroll
        for (int n = 0; n < 8; ++n) acc[m][n] = (f32x4){0.f, 0.f, 0.f, 0.f};

    float4 LA[4], LB[4];
    bf16x8 bA[8], bB[8];
    // prologue: a & b for kk=0
#pragma unroll
    for (int m = 0; m < 2; ++m) {
        const float* p = aSrc + (size_t)m * 16 * 512;
        LA[m * 2]     = *(const float4*)p;
        LA[m * 2 + 1] = *(const float4*)(p + 4);
    }
#pragma unroll
    for (int n = 0; n < 8; ++n)
        bA[n] = *(const bf16x8*)(Wbb + bOffBase + n * 1024);

#pragma unroll 1
    for (int kk2 = 0; kk2 < 8; ++kk2) {
        {   // ---- half A: compute kk=2*kk2; prefetch a,b for kk+1 ----
            const int kk = 2 * kk2;
            const char* Wn = Wbb + ((size_t)(kk + 1) << 15);
#pragma unroll
            for (int n = 0; n < 8; ++n)
                bB[n] = *(const bf16x8*)(Wn + bOffBase + n * 1024);
#pragma unroll
            for (int m = 0; m < 2; ++m) {
                const float* p = aSrc + (size_t)m * 16 * 512 + (kk + 1) * 32;
                LB[m * 2]     = *(const float4*)p;
                LB[m * 2 + 1] = *(const float4*)(p + 4);
            }
            bf16x8 af[2];
            af[0] = cvt8(LA[0], LA[1]);
            af[1] = cvt8(LA[2], LA[3]);
            if (w == (kk & 3)) {   // designated wave builds the bf16 A-copy
#pragma unroll
                for (int m = 0; m < 2; ++m)
                    *(bf16x8*)(smem + (m * 16 + l15) * 1024 + (kk * 4 + lhi) * 16) = af[m];
            }
#pragma unroll
            for (int m = 0; m < 2; ++m)
#pragma unroll
                for (int n = 0; n < 8; ++n)
                    acc[m][n] = __builtin_amdgcn_mfma_f32_16x16x32_bf16(af[m], bA[n], acc[m][n], 0, 0, 0);
        }
        {   // ---- half B: compute kk=2*kk2+1; prefetch a,b for kk+2 ----
            const int kk = 2 * kk2 + 1;
            if (kk2 < 7) {
                const char* Wn = Wbb + ((size_t)(kk + 1) << 15);
#pragma unroll
                for (int n = 0; n < 8; ++n)
                    bA[n] = *(const bf16x8*)(Wn + bOffBase + n * 1024);
#pragma unroll
                for (int m = 0; m < 2; ++m) {
                    const float* p = aSrc + (size_t)m * 16 * 512 + (kk + 1) * 32;
                    LA[m * 2]     = *(const float4*)p;
                    LA[m * 2 + 1] = *(const float4*)(p + 4);
                }
            }
            bf16x8 af[2];
            af[0] = cvt8(LB[0], LB[1]);
            af[1] = cvt8(LB[2], LB[3]);
            if (w == (kk & 3)) {
#pragma unroll
                for (int m = 0; m < 2; ++m)
                    *(bf16x8*)(smem + (m * 16 + l15) * 1024 + (kk * 4 + lhi) * 16) = af[m];
            }
#pragma unroll
            for (int m = 0; m < 2; ++m)
#pragma unroll
                for (int n = 0; n < 8; ++n)
                    acc[m][n] = __builtin_amdgcn_mfma_f32_16x16x32_bf16(af[m], bB[n], acc[m][n], 0, 0, 0);
        }
    }

    // ---- epilogue: beta-partial[row] over this wave's 128 cols ----
    float bsum[2][4];
#pragma unroll
    for (int m = 0; m < 2; ++m)
#pragma unroll
        for (int r = 0; r < 4; ++r) {
            float s = 0.f;
#pragma unroll
            for (int n = 0; n < 8; ++n)
                s += Vv[n] * fast_tanh(acc[m][n][r]);
            bsum[m][r] = s;
        }
#pragma unroll
    for (int off = 1; off <= 8; off <<= 1)
#pragma unroll
        for (int m = 0; m < 2; ++m)
#pragma unroll
            for (int r = 0; r < 4; ++r)
                bsum[m][r] += __shfl_xor(bsum[m][r], off, 64);

    float* betaP = (float*)(smem + BETA_OFF);   // [4 col-groups][32 rows]
    if (l15 == 0) {
#pragma unroll
        for (int m = 0; m < 2; ++m)
#pragma unroll
            for (int r = 0; r < 4; ++r)
                betaP[w * BM + m * 16 + lhi * 4 + r] = bsum[m][r];
    }
    __syncthreads();

    // ---- eb = exp(beta); S[g] += eb (lanes 0-31 of wave 0; rows sorted) ----
    float* ebs  = (float*)(smem + EBS_OFF);
    int*   sidx = (int*)(smem + SIDX_OFF);
    if (tid < BM) {
        float beta = betaP[tid] + betaP[BM + tid] + betaP[2 * BM + tid] + betaP[3 * BM + tid];
        float eb = expf(beta);
        ebs[tid] = eb;
        int g = BI[nodeBase + tid];
        sidx[tid] = g;
        int g0 = __shfl(g, 0, 32);
        if (__all(g == g0)) {
            float s = eb;
#pragma unroll
            for (int off = 1; off <= 16; off <<= 1)
                s += __shfl_xor(s, off, 32);
            if (tid == 0) atomicAdd(&S[g], s);
        } else {
            atomicAdd(&S[g], eb);
        }
    }
    __syncthreads();

    // ---- weighted segment sum: wave w owns rows [8w,+8); lane l cols [8l,+8).
    // Flush transposes through per-wave 1KB scr (2 passes) -> lane-contiguous atomics.
    {
        float* scr = (float*)(smem + SCR_OFF) + w * 256;
        const int rbase = w * 8;
        float a8[8];
#pragma unroll
        for (int j = 0; j < 8; ++j) a8[j] = 0.f;
        int gcur = sidx[rbase];

        auto flush = [&](int gseg) {
#pragma unroll
            for (int q = 0; q < 2; ++q) {     // cols [q*256, q*256+256)
                if ((l >> 5) == q) {
                    *(float4*)(scr + (l & 31) * 8)     = make_float4(a8[0], a8[1], a8[2], a8[3]);
                    *(float4*)(scr + (l & 31) * 8 + 4) = make_float4(a8[4], a8[5], a8[6], a8[7]);
                }
                asm volatile("s_waitcnt lgkmcnt(0)" ::: "memory");
#pragma unroll
                for (int j2 = 0; j2 < 4; ++j2)
                    atomicAdd(&out[(size_t)gseg * 512 + q * 256 + j2 * 64 + l],
                              scr[j2 * 64 + l]);
                __builtin_amdgcn_sched_barrier(0);
            }
        };

#pragma unroll 1
        for (int rr = 0; rr < 8; ++rr) {
            int r = rbase + rr;
            int g = sidx[r];                     // wave-uniform
            if (g != gcur) {
                flush(gcur);
#pragma unroll
                for (int j = 0; j < 8; ++j) a8[j] = 0.f;
                gcur = g;
            }
            float wgt = ebs[r];
            bf16x8 v = *(const bf16x8*)(smem + r * 1024 + l * 16);
#pragma unroll
            for (int j = 0; j < 8; ++j)
                a8[j] += wgt * bf2f((u16)v[j]);
        }
        flush(gcur);
    }
}

__global__ __launch_bounds__(256)
void finalize_kernel(float* __restrict__ out, const float* __restrict__ S) {
    int idx = blockIdx.x * 256 + threadIdx.x;
    float s = S[idx >> 9];
    float v = out[idx];
    out[idx] = (s != 0.f) ? v * __builtin_amdgcn_rcpf(s) : 0.f;
}

extern "C" void kernel_launch(void* const* d_in, const int* in_sizes, int n_in,
                              void* d_out, int out_size, void* d_ws, size_t ws_size,
                              hipStream_t stream) {
    const float* E  = (const float*)d_in[0];
    const int*   BI = (const int*)d_in[1];
    const float* W  = (const float*)d_in[2];
    const float* V  = (const float*)d_in[3];
    float* out = (float*)d_out;
    char*  ws  = (char*)d_ws;
    const int Ntot = in_sizes[0] / D_DIM;

    float* S  = (float*)(ws + WS_S);
    u16*   Wb = (u16*)(ws + WS_WB);

    hipMemsetAsync(S, 0, G_SEG * 4, stream);
    hipMemsetAsync(out, 0, (size_t)out_size * 4, stream);

    cvt_w<<<128, 256, 0, stream>>>(W, Wb);
    fused<<<Ntot / BM, 256, 0, stream>>>(E, BI, Wb, V, out, S);
    finalize_kernel<<<out_size / 256, 256, 0, stream>>>(out, S);
}

// Round 14
// 724.977 us; speedup vs baseline: 3.0978x; 3.0978x over previous
//
#include <hip/hip_runtime.h>
#include <hip/hip_bf16.h>

#define D_DIM 512
#define H_DIM 512
#define G_SEG 1024
#define BM    32

typedef __attribute__((ext_vector_type(8))) short bf16x8;
typedef __attribute__((ext_vector_type(4))) float f32x4;
typedef unsigned int u32;
typedef unsigned short u16;

// ---- workspace ----
#define WS_S   0         // G f32
#define WS_WB  8192      // 512 KB bf16 W in MFMA-fragment granule layout

// ---- LDS: bf16 A-copy (linear granules) + beta/ebs/sidx + per-wave scratch ----
#define AS_BYTES  (BM * 1024)                 // 32 rows x 64 granules x 16B
#define BETA_OFF  AS_BYTES                    // 8 col-groups x 32 f32
#define EBS_OFF   (BETA_OFF + 8 * BM * 4)
#define SIDX_OFF  (EBS_OFF + BM * 4)
#define SCR_OFF   (SIDX_OFF + BM * 4)         // 8 waves x 1KB
#define LDS_TOTAL (SCR_OFF + 8 * 1024)        // 42240 B -> 2 blocks/CU easily

static __device__ __forceinline__ u16 f2bf(float f) {
    __hip_bfloat16 h = __float2bfloat16(f);
    return *(u16*)&h;
}
static __device__ __forceinline__ float bf2f(u16 u) {
    return __uint_as_float(((u32)u) << 16);
}
static __device__ __forceinline__ float fast_tanh(float x) {
    float e = exp2f(x * 2.885390081777927f);   // e^(2x)
    return 1.0f - 2.0f * __builtin_amdgcn_rcpf(e + 1.0f);
}
static __device__ __forceinline__ bf16x8 cvt8(const float4& a, const float4& b) {
    union { u16 h[8]; bf16x8 v; } u;
    u.h[0]=f2bf(a.x); u.h[1]=f2bf(a.y); u.h[2]=f2bf(a.z); u.h[3]=f2bf(a.w);
    u.h[4]=f2bf(b.x); u.h[5]=f2bf(b.y); u.h[6]=f2bf(b.z); u.h[7]=f2bf(b.w);
    return u.v;
}

// ---- W fp32 -> bf16 granule layout: byte ((k32*512 + c)*4 + lhi)*16 ----
__global__ __launch_bounds__(256)
void cvt_w(const float* __restrict__ W, u16* __restrict__ Wb) {
    int t   = blockIdx.x * 256 + threadIdx.x;
    int lhi = t & 3;
    int c   = (t >> 2) & 511;
    int k32 = t >> 11;
    const float* src = W + (size_t)c * 512 + k32 * 32 + lhi * 8;
    bf16x8 v = cvt8(*(const float4*)src, *(const float4*)(src + 4));
    *(bf16x8*)(Wb + (size_t)t * 8) = v;
}

// ---- fused: 32-row tile, 8 waves x (32 rows x 64 cols), barrier-free K-loop,
// A global->reg->cvt (L2-warm), b reg-dbuf, 4 waves/SIMD, no spill by design.
__global__ __launch_bounds__(512, 4)
void fused(const float* __restrict__ E, const int* __restrict__ BI,
           const u16* __restrict__ Wb, const float* __restrict__ V,
           float* __restrict__ out, float* __restrict__ S)
{
    __shared__ char smem[LDS_TOTAL];
    const int tid = threadIdx.x;
    const int l   = tid & 63;
    const int w   = tid >> 6;     // col group: cols [w*64, +64)
    const int l15 = l & 15;
    const int lhi = l >> 4;
    const int nodeBase = blockIdx.x * BM;

    const float* aSrc = E + (size_t)nodeBase * 512 + (size_t)l15 * 512 + lhi * 8;
    const int bOffBase = ((w * 64 + l15) * 4 + lhi) * 16;   // + n*1024, n<4
    const char* Wbb = (const char*)Wb;

    float Vv[4];
#pragma unroll
    for (int n = 0; n < 4; ++n)
        Vv[n] = V[w * 64 + n * 16 + l15];

    f32x4 acc[2][4];
#pragma unroll
    for (int m = 0; m < 2; ++m)
#pragma unroll
        for (int n = 0; n < 4; ++n) acc[m][n] = (f32x4){0.f, 0.f, 0.f, 0.f};

    float4 LA[4];
    bf16x8 bA[4], bB[4];
    // prologue: a(kk=0), b(kk=0)
#pragma unroll
    for (int m = 0; m < 2; ++m) {
        const float* p = aSrc + (size_t)m * 16 * 512;
        LA[m * 2]     = *(const float4*)p;
        LA[m * 2 + 1] = *(const float4*)(p + 4);
    }
#pragma unroll
    for (int n = 0; n < 4; ++n)
        bA[n] = *(const bf16x8*)(Wbb + bOffBase + n * 1024);

#pragma unroll 1
    for (int kk2 = 0; kk2 < 8; ++kk2) {
        {   // ---- half A: kk = 2*kk2 (consume LA, bA); prefetch bB, LA(kk+1)
            const int kk = 2 * kk2;
            const char* Wn = Wbb + ((size_t)(kk + 1) << 15);
#pragma unroll
            for (int n = 0; n < 4; ++n)
                bB[n] = *(const bf16x8*)(Wn + bOffBase + n * 1024);
            bf16x8 af[2];
            af[0] = cvt8(LA[0], LA[1]);
            af[1] = cvt8(LA[2], LA[3]);
#pragma unroll
            for (int m = 0; m < 2; ++m) {
                const float* p = aSrc + (size_t)m * 16 * 512 + (kk + 1) * 32;
                LA[m * 2]     = *(const float4*)p;
                LA[m * 2 + 1] = *(const float4*)(p + 4);
            }
            if (w == (kk & 7)) {   // designated wave builds bf16 A-copy
#pragma unroll
                for (int m = 0; m < 2; ++m)
                    *(bf16x8*)(smem + (m * 16 + l15) * 1024 + (kk * 4 + lhi) * 16) = af[m];
            }
#pragma unroll
            for (int m = 0; m < 2; ++m)
#pragma unroll
                for (int n = 0; n < 4; ++n)
                    acc[m][n] = __builtin_amdgcn_mfma_f32_16x16x32_bf16(af[m], bA[n], acc[m][n], 0, 0, 0);
        }
        {   // ---- half B: kk = 2*kk2+1 (consume LA, bB); prefetch bA, LA(kk+1)
            const int kk = 2 * kk2 + 1;
            if (kk2 < 7) {
                const char* Wn = Wbb + ((size_t)(kk + 1) << 15);
#pragma unroll
                for (int n = 0; n < 4; ++n)
                    bA[n] = *(const bf16x8*)(Wn + bOffBase + n * 1024);
            }
            bf16x8 af[2];
            af[0] = cvt8(LA[0], LA[1]);
            af[1] = cvt8(LA[2], LA[3]);
            if (kk2 < 7) {
#pragma unroll
                for (int m = 0; m < 2; ++m) {
                    const float* p = aSrc + (size_t)m * 16 * 512 + (kk + 1) * 32;
                    LA[m * 2]     = *(const float4*)p;
                    LA[m * 2 + 1] = *(const float4*)(p + 4);
                }
            }
            if (w == (kk & 7)) {
#pragma unroll
                for (int m = 0; m < 2; ++m)
                    *(bf16x8*)(smem + (m * 16 + l15) * 1024 + (kk * 4 + lhi) * 16) = af[m];
            }
#pragma unroll
            for (int m = 0; m < 2; ++m)
#pragma unroll
                for (int n = 0; n < 4; ++n)
                    acc[m][n] = __builtin_amdgcn_mfma_f32_16x16x32_bf16(af[m], bB[n], acc[m][n], 0, 0, 0);
        }
    }

    // ---- epilogue: beta-partial[row] over this wave's 64 cols ----
    float bsum[2][4];
#pragma unroll
    for (int m = 0; m < 2; ++m)
#pragma unroll
        for (int r = 0; r < 4; ++r) {
            float s = 0.f;
#pragma unroll
            for (int n = 0; n < 4; ++n)
                s += Vv[n] * fast_tanh(acc[m][n][r]);
            bsum[m][r] = s;
        }
#pragma unroll
    for (int off = 1; off <= 8; off <<= 1)
#pragma unroll
        for (int m = 0; m < 2; ++m)
#pragma unroll
            for (int r = 0; r < 4; ++r)
                bsum[m][r] += __shfl_xor(bsum[m][r], off, 64);

    float* betaP = (float*)(smem + BETA_OFF);   // [8 col-groups][32 rows]
    if (l15 == 0) {
#pragma unroll
        for (int m = 0; m < 2; ++m)
#pragma unroll
            for (int r = 0; r < 4; ++r)
                betaP[w * BM + m * 16 + lhi * 4 + r] = bsum[m][r];
    }
    __syncthreads();

    // ---- eb = exp(beta); S[g] += eb (threads 0-31; rows sorted) ----
    float* ebs  = (float*)(smem + EBS_OFF);
    int*   sidx = (int*)(smem + SIDX_OFF);
    if (tid < BM) {
        float beta = 0.f;
#pragma unroll
        for (int j = 0; j < 8; ++j)
            beta += betaP[j * BM + tid];
        float eb = expf(beta);
        ebs[tid] = eb;
        int g = BI[nodeBase + tid];
        sidx[tid] = g;
        int g0 = __shfl(g, 0, 32);
        if (__all(g == g0)) {
            float s = eb;
#pragma unroll
            for (int off = 1; off <= 16; off <<= 1)
                s += __shfl_xor(s, off, 32);
            if (tid == 0) atomicAdd(&S[g], s);
        } else {
            atomicAdd(&S[g], eb);
        }
    }
    __syncthreads();

    // ---- weighted segment sum: wave w rows [4w,+4); lane l cols [8l,+8).
    // Flush transposes through per-wave 1KB scr (2 passes) -> lane-contiguous atomics.
    {
        float* scr = (float*)(smem + SCR_OFF) + w * 256;
        const int rbase = w * 4;
        float a8[8];
#pragma unroll
        for (int j = 0; j < 8; ++j) a8[j] = 0.f;
        int gcur = sidx[rbase];

        auto flush = [&](int gseg) {
#pragma unroll
            for (int q = 0; q < 2; ++q) {     // cols [q*256, q*256+256)
                if ((l >> 5) == q) {
                    *(float4*)(scr + (l & 31) * 8)     = make_float4(a8[0], a8[1], a8[2], a8[3]);
                    *(float4*)(scr + (l & 31) * 8 + 4) = make_float4(a8[4], a8[5], a8[6], a8[7]);
                }
                asm volatile("s_waitcnt lgkmcnt(0)" ::: "memory");
#pragma unroll
                for (int j2 = 0; j2 < 4; ++j2)
                    atomicAdd(&out[(size_t)gseg * 512 + q * 256 + j2 * 64 + l],
                              scr[j2 * 64 + l]);
                __builtin_amdgcn_sched_barrier(0);
            }
        };

#pragma unroll 1
        for (int rr = 0; rr < 4; ++rr) {
            int r = rbase + rr;
            int g = sidx[r];                     // wave-uniform
            if (g != gcur) {
                flush(gcur);
#pragma unroll
                for (int j = 0; j < 8; ++j) a8[j] = 0.f;
                gcur = g;
            }
            float wgt = ebs[r];
            bf16x8 v = *(const bf16x8*)(smem + r * 1024 + l * 16);
#pragma unroll
            for (int j = 0; j < 8; ++j)
                a8[j] += wgt * bf2f((u16)v[j]);
        }
        flush(gcur);
    }
}

__global__ __launch_bounds__(256)
void finalize_kernel(float* __restrict__ out, const float* __restrict__ S) {
    int idx = blockIdx.x * 256 + threadIdx.x;
    float s = S[idx >> 9];
    float v = out[idx];
    out[idx] = (s != 0.f) ? v * __builtin_amdgcn_rcpf(s) : 0.f;
}

extern "C" void kernel_launch(void* const* d_in, const int* in_sizes, int n_in,
                              void* d_out, int out_size, void* d_ws, size_t ws_size,
                              hipStream_t stream) {
    const float* E  = (const float*)d_in[0];
    const int*   BI = (const int*)d_in[1];
    const float* W  = (const float*)d_in[2];
    const float* V  = (const float*)d_in[3];
    float* out = (float*)d_out;
    char*  ws  = (char*)d_ws;
    const int Ntot = in_sizes[0] / D_DIM;

    float* S  = (float*)(ws + WS_S);
    u16*   Wb = (u16*)(ws + WS_WB);

    hipMemsetAsync(S, 0, G_SEG * 4, stream);
    hipMemsetAsync(out, 0, (size_t)out_size * 4, stream);

    cvt_w<<<128, 256, 0, stream>>>(W, Wb);
    fused<<<Ntot / BM, 512, 0, stream>>>(E, BI, Wb, V, out, S);
    finalize_kernel<<<out_size / 256, 256, 0, stream>>>(out, S);
}